// Round 1
// baseline (918.643 us; speedup 1.0000x reference)
//
#include <hip/hip_runtime.h>
#include <stdint.h>

#define B_N 2
#define S_N 2048
#define D_N 4096
#define H_N 32
#define KVH_N 8
#define HD_N 128
#define QK_SCALE 0.08838834764831845f

typedef __attribute__((ext_vector_type(8))) short bf16x8;
typedef __attribute__((ext_vector_type(4))) float f32x4;

__device__ __forceinline__ unsigned short f2bf(float f) {
    union { float f; unsigned u; } v; v.f = f;
    unsigned u = v.u;
    u += 0x7fffu + ((u >> 16) & 1u);   // RNE
    return (unsigned short)(u >> 16);
}
__device__ __forceinline__ float bf2f(unsigned short h) {
    union { unsigned u; float f; } v; v.u = ((unsigned)h) << 16;
    return v.f;
}

__device__ __forceinline__ void gl16(const unsigned short* g, unsigned short* l) {
    __builtin_amdgcn_global_load_lds(
        (const __attribute__((address_space(1))) void*)g,
        (__attribute__((address_space(3))) void*)l, 16, 0, 0);
}

// ---------------- f32 -> bf16 conversion (vectorized) ----------------
__global__ void __launch_bounds__(256) conv_f32_bf16(const float* __restrict__ in,
                                                     unsigned short* __restrict__ out) {
    int i = (blockIdx.x * 256 + threadIdx.x) * 4;
    float4 v = *(const float4*)(in + i);
    ushort4 o;
    o.x = f2bf(v.x); o.y = f2bf(v.y); o.z = f2bf(v.z); o.w = f2bf(v.w);
    *(ushort4*)(out + i) = o;
}

// ---------------- RoPE (in-place on bf16, pairs are adjacent) ----------------
template<int HEADS, int STRIDE>
__global__ void __launch_bounds__(256) rope_kernel(unsigned short* __restrict__ t,
                                                   const float* __restrict__ cosb,
                                                   const float* __restrict__ sinb,
                                                   float scale) {
    int p = blockIdx.x * 256 + threadIdx.x;
    int i = p & 63;                 // pair index within head dim
    int hr = p >> 6;                // head-row
    int m = hr / HEADS;             // b*S + s
    int hh = hr - m * HEADS;
    int s = m & (S_N - 1);
    size_t off = (size_t)m * STRIDE + hh * HD_N + 2 * i;
    unsigned v = *(const unsigned*)(t + off);
    float t0 = bf2f((unsigned short)(v & 0xffffu));
    float t1 = bf2f((unsigned short)(v >> 16));
    float c = cosb[s * 64 + i], sn = sinb[s * 64 + i];
    float o0 = (t0 * c - t1 * sn) * scale;
    float o1 = (t0 * sn + t1 * c) * scale;
    *(unsigned*)(t + off) = (unsigned)f2bf(o0) | ((unsigned)f2bf(o1) << 16);
}

// ---------------- NT GEMM: C[m][n] = sum_k A[m][k]*B[n][k]  (m97 structure) ----------------
// A: M x K bf16 row-major, B: N x K bf16 row-major. 128x128 tile, BK=32, 4 waves.
template<int F32OUT>
__global__ void __launch_bounds__(256) gemm_bt(const unsigned short* __restrict__ A,
                                               const unsigned short* __restrict__ Bm,
                                               void* __restrict__ Cv,
                                               int M, int N, int K) {
    __shared__ unsigned short As[128 * 32];
    __shared__ unsigned short Bs[128 * 32];

    const int nb = N >> 7;
    const int bm = blockIdx.x / nb, bn = blockIdx.x - bm * nb;
    const int tid = threadIdx.x;
    const int w = tid >> 6, lane = tid & 63;
    const int li = lane & 15, lg = lane >> 4;
    const int wm = w >> 1, wn = w & 1;

    f32x4 acc[4][4];
#pragma unroll
    for (int i = 0; i < 4; ++i)
#pragma unroll
        for (int j = 0; j < 4; ++j) acc[i][j] = (f32x4){0.f, 0.f, 0.f, 0.f};

    // staging geometry: wave w, issue j covers LDS bytes [(w*2+j)*1024, +1024)
    const int srow = w * 32 + (lane >> 2);      // j=0 rows; j=1 adds +16
    const int scol = (lane & 3) * 8;            // elems
    const unsigned short* Ag0 = A + (size_t)(bm * 128 + srow) * K + scol;
    const unsigned short* Ag1 = Ag0 + (size_t)16 * K;
    const unsigned short* Bg0 = Bm + (size_t)(bn * 128 + srow) * K + scol;
    const unsigned short* Bg1 = Bg0 + (size_t)16 * K;
    unsigned short* Asl0 = &As[(w * 2 + 0) * 512];
    unsigned short* Asl1 = &As[(w * 2 + 1) * 512];
    unsigned short* Bsl0 = &Bs[(w * 2 + 0) * 512];
    unsigned short* Bsl1 = &Bs[(w * 2 + 1) * 512];

    for (int k0 = 0; k0 < K; k0 += 32) {
        gl16(Ag0 + k0, Asl0);
        gl16(Ag1 + k0, Asl1);
        gl16(Bg0 + k0, Bsl0);
        gl16(Bg1 + k0, Bsl1);
        __syncthreads();

        bf16x8 af[4], bfr[4];
#pragma unroll
        for (int mi = 0; mi < 4; ++mi)
            af[mi] = *(const bf16x8*)&As[(wm * 64 + mi * 16 + li) * 32 + lg * 8];
#pragma unroll
        for (int ni = 0; ni < 4; ++ni)
            bfr[ni] = *(const bf16x8*)&Bs[(wn * 64 + ni * 16 + li) * 32 + lg * 8];
#pragma unroll
        for (int mi = 0; mi < 4; ++mi)
#pragma unroll
            for (int ni = 0; ni < 4; ++ni)
                acc[mi][ni] = __builtin_amdgcn_mfma_f32_16x16x32_bf16(af[mi], bfr[ni], acc[mi][ni], 0, 0, 0);
        __syncthreads();
    }

    const int r0 = bm * 128 + wm * 64 + lg * 4;
    const int c0 = bn * 128 + wn * 64 + li;
    if (F32OUT) {
        float* C = (float*)Cv;
#pragma unroll
        for (int mi = 0; mi < 4; ++mi)
#pragma unroll
            for (int ni = 0; ni < 4; ++ni)
#pragma unroll
                for (int r = 0; r < 4; ++r)
                    C[(size_t)(r0 + mi * 16 + r) * N + c0 + ni * 16] = acc[mi][ni][r];
    } else {
        unsigned short* C = (unsigned short*)Cv;
#pragma unroll
        for (int mi = 0; mi < 4; ++mi)
#pragma unroll
            for (int ni = 0; ni < 4; ++ni)
#pragma unroll
                for (int r = 0; r < 4; ++r)
                    C[(size_t)(r0 + mi * 16 + r) * N + c0 + ni * 16] = f2bf(acc[mi][ni][r]);
    }
}

// ---------------- Flash attention, causal, GQA 4:1 ----------------
// Q: (B*S, 4096) bf16 (scale pre-folded); K/V inside KV: (B*S, 2048), V offset +1024.
// Grid: (S/64, B*H). 4 waves; wave w owns q rows [w*16, w*16+16).
__global__ void __launch_bounds__(256) attn_kernel(const unsigned short* __restrict__ Q,
                                                   const unsigned short* __restrict__ Kb,
                                                   const unsigned short* __restrict__ Vb,
                                                   unsigned short* __restrict__ O) {
    __shared__ unsigned short Ks[64 * 128];   // [kv][d], rows 256B, swizzled by (kv&7)
    __shared__ unsigned short Vt[128 * 64];   // [d][kv], rows 128B, swizzled by ((d^d>>3)&7)
    __shared__ unsigned short Ps[64 * 64];    // [q][kv], rows 128B, swizzled by (q&7)

    const int qt = blockIdx.x;
    const int bh = blockIdx.y;
    const int b = bh >> 5, h = bh & 31;
    const int kvh = h >> 2;
    const int tid = threadIdx.x;
    const int w = tid >> 6, lane = tid & 63;
    const int li = lane & 15, lg = lane >> 4;

    // Q fragments (registers, whole block lifetime)
    bf16x8 qf[4];
    {
        const unsigned short* qp = Q + ((size_t)(b * S_N) + qt * 64 + w * 16 + li) * (H_N * HD_N)
                                     + h * HD_N + lg * 8;
#pragma unroll
        for (int ds = 0; ds < 4; ++ds) qf[ds] = *(const bf16x8*)(qp + ds * 32);
    }

    float mreg[4], lreg[4];
#pragma unroll
    for (int r = 0; r < 4; ++r) { mreg[r] = -1e30f; lreg[r] = 0.f; }
    f32x4 o_acc[8];
#pragma unroll
    for (int di = 0; di < 8; ++di) o_acc[di] = (f32x4){0.f, 0.f, 0.f, 0.f};

    for (int kt = 0; kt <= qt; ++kt) {
        // ---- stage K tile [64][128] (row-swizzled) ----
#pragma unroll
        for (int it = 0; it < 4; ++it) {
            int o_ = it * 4096 + tid * 16;         // byte offset in [64][256B]
            int row = o_ >> 8;
            int colb = o_ & 255;
            uint4 v = *(const uint4*)(Kb + ((size_t)(b * S_N) + kt * 64 + row) * 2048
                                        + kvh * 128 + (colb >> 1));
            *(uint4*)((char*)Ks + row * 256 + (colb ^ ((row & 7) << 4))) = v;
        }
        // ---- stage V^T tile [128][64] (dual-key swizzle) ----
#pragma unroll
        for (int it = 0; it < 2; ++it) {
            int c = it * 256 + tid;                // 512 chunks: 32 row-pairs x 16 col-chunks
            int rp = c >> 4;
            int cc = c & 15;
            int kv = rp * 2;
            int d0 = cc * 8;
            const unsigned short* vp = Vb + ((size_t)(b * S_N) + kt * 64 + kv) * 2048
                                          + kvh * 128 + d0;
            union { uint4 q; unsigned short u[8]; } a0, a1;
            a0.q = *(const uint4*)vp;
            a1.q = *(const uint4*)(vp + 2048);
#pragma unroll
            for (int jj = 0; jj < 8; ++jj) {
                int d = d0 + jj;
                unsigned pack = (unsigned)a0.u[jj] | ((unsigned)a1.u[jj] << 16);
                int key = ((d ^ (d >> 3)) & 7) << 4;
                *(unsigned*)((char*)Vt + d * 128 + ((kv * 2) ^ key)) = pack;
            }
        }
        __syncthreads();

        // ---- S = Q K^T (per wave: 16 q rows x 64 kv) ----
        f32x4 sf[4];
#pragma unroll
        for (int ni = 0; ni < 4; ++ni) sf[ni] = (f32x4){0.f, 0.f, 0.f, 0.f};
#pragma unroll
        for (int ni = 0; ni < 4; ++ni) {
            int kvc = ni * 16 + li;
#pragma unroll
            for (int ds = 0; ds < 4; ++ds) {
                bf16x8 kf = *(const bf16x8*)((char*)Ks + kvc * 256
                                             + ((ds * 64 + lg * 16) ^ ((kvc & 7) << 4)));
                sf[ni] = __builtin_amdgcn_mfma_f32_16x16x32_bf16(qf[ds], kf, sf[ni], 0, 0, 0);
            }
        }

        // ---- causal mask on diagonal tile ----
        if (kt == qt) {
#pragma unroll
            for (int ni = 0; ni < 4; ++ni) {
                int kvc = ni * 16 + li;
#pragma unroll
                for (int r = 0; r < 4; ++r) {
                    int qg = w * 16 + lg * 4 + r;
                    if (kvc > qg) sf[ni][r] = -1e30f;
                }
            }
        }

        // ---- online softmax (rows live in 16-lane groups) ----
        float fac[4];
#pragma unroll
        for (int r = 0; r < 4; ++r) {
            float pm = fmaxf(fmaxf(sf[0][r], sf[1][r]), fmaxf(sf[2][r], sf[3][r]));
            pm = fmaxf(pm, __shfl_xor(pm, 1));
            pm = fmaxf(pm, __shfl_xor(pm, 2));
            pm = fmaxf(pm, __shfl_xor(pm, 4));
            pm = fmaxf(pm, __shfl_xor(pm, 8));
            float mn = fmaxf(mreg[r], pm);
            fac[r] = __expf(mreg[r] - mn);
            mreg[r] = mn;
        }
#pragma unroll
        for (int ni = 0; ni < 4; ++ni)
#pragma unroll
            for (int r = 0; r < 4; ++r)
                sf[ni][r] = __expf(sf[ni][r] - mreg[r]);
#pragma unroll
        for (int r = 0; r < 4; ++r) {
            float s = sf[0][r] + sf[1][r] + sf[2][r] + sf[3][r];
            s += __shfl_xor(s, 1);
            s += __shfl_xor(s, 2);
            s += __shfl_xor(s, 4);
            s += __shfl_xor(s, 8);
            lreg[r] = lreg[r] * fac[r] + s;
        }
#pragma unroll
        for (int di = 0; di < 8; ++di)
#pragma unroll
            for (int r = 0; r < 4; ++r) o_acc[di][r] *= fac[r];

        // ---- P -> LDS (wave-private rows; in-wave DS ordering) ----
#pragma unroll
        for (int ni = 0; ni < 4; ++ni) {
#pragma unroll
            for (int r = 0; r < 4; ++r) {
                int q = w * 16 + lg * 4 + r;
                int kv = ni * 16 + li;
                *(unsigned short*)((char*)Ps + q * 128 + ((kv * 2) ^ ((q & 7) << 4)))
                    = f2bf(sf[ni][r]);
            }
        }

        // ---- O += P V ----
#pragma unroll
        for (int ks = 0; ks < 2; ++ks) {
            int q = w * 16 + li;
            bf16x8 pf = *(const bf16x8*)((char*)Ps + q * 128
                                         + ((ks * 64 + lg * 16) ^ ((q & 7) << 4)));
#pragma unroll
            for (int di = 0; di < 8; ++di) {
                int d = di * 16 + li;
                int key = ((d ^ (d >> 3)) & 7) << 4;
                bf16x8 vf = *(const bf16x8*)((char*)Vt + d * 128
                                             + ((ks * 64 + lg * 16) ^ key));
                o_acc[di] = __builtin_amdgcn_mfma_f32_16x16x32_bf16(pf, vf, o_acc[di], 0, 0, 0);
            }
        }
        __syncthreads();
    }

    // ---- epilogue: divide by row sums, write O (aliases Q region of this block) ----
#pragma unroll
    for (int r = 0; r < 4; ++r) lreg[r] = 1.f / lreg[r];
    unsigned short* op = O + ((size_t)(b * S_N) + qt * 64 + w * 16 + lg * 4) * (H_N * HD_N)
                           + h * HD_N + li;
#pragma unroll
    for (int di = 0; di < 8; ++di)
#pragma unroll
        for (int r = 0; r < 4; ++r)
            op[(size_t)r * (H_N * HD_N) + di * 16] = f2bf(o_acc[di][r] * lreg[r]);
}

// ---------------- launch ----------------
extern "C" void kernel_launch(void* const* d_in, const int* in_sizes, int n_in,
                              void* d_out, int out_size, void* d_ws, size_t ws_size,
                              hipStream_t stream) {
    (void)in_sizes; (void)n_in; (void)out_size; (void)ws_size;
    const float* x  = (const float*)d_in[0];
    const float* wq = (const float*)d_in[1];
    const float* wk = (const float*)d_in[2];
    const float* wv = (const float*)d_in[3];
    const float* wo = (const float*)d_in[4];
    const float* fc = (const float*)d_in[5];
    const float* fs = (const float*)d_in[6];
    float* out = (float*)d_out;

    char* ws = (char*)d_ws;
    unsigned short* xb  = (unsigned short*)(ws);                // 33.5MB  x bf16
    unsigned short* wb  = (unsigned short*)(ws + 33554432);     // 33.5MB  wq, later wo
    unsigned short* wkv = (unsigned short*)(ws + 67108864);     // 16.8MB  [wk;wv]
    unsigned short* Qb  = (unsigned short*)(ws + 83886080);     // 33.5MB  Q, later attn-O
    unsigned short* KVb = (unsigned short*)(ws + 117440512);    // 16.8MB  [K|V] rows of 2048
    // total: 128 MiB

    const int BS = B_N * S_N;  // 4096

    // f32 -> bf16
    conv_f32_bf16<<<dim3(BS * D_N / 1024), 256, 0, stream>>>(x, xb);
    conv_f32_bf16<<<dim3(H_N * HD_N * D_N / 1024), 256, 0, stream>>>(wq, wb);
    conv_f32_bf16<<<dim3(KVH_N * HD_N * D_N / 1024), 256, 0, stream>>>(wk, wkv);
    conv_f32_bf16<<<dim3(KVH_N * HD_N * D_N / 1024), 256, 0, stream>>>(wv, wkv + KVH_N * HD_N * D_N);

    // Q = x wq^T  (bf16 out)
    gemm_bt<0><<<dim3((BS / 128) * (D_N / 128)), 256, 0, stream>>>(xb, wb, Qb, BS, D_N, D_N);
    // wo -> wb (stream-ordered after Q gemm)
    conv_f32_bf16<<<dim3(D_N * H_N * HD_N / 1024), 256, 0, stream>>>(wo, wb);
    // [K|V] = x [wk;wv]^T  (bf16 out, N=2048)
    gemm_bt<0><<<dim3((BS / 128) * (2048 / 128)), 256, 0, stream>>>(xb, wkv, KVb, BS, 2048, D_N);

    // RoPE: Q (scale folded), K
    rope_kernel<H_N, H_N * HD_N><<<dim3(BS * H_N * 64 / 256), 256, 0, stream>>>(Qb, fc, fs, QK_SCALE);
    rope_kernel<KVH_N, 2 * KVH_N * HD_N><<<dim3(BS * KVH_N * 64 / 256), 256, 0, stream>>>(KVb, fc, fs, 1.0f);

    // attention (writes O in-place over Qb; per-block read-before-write)
    attn_kernel<<<dim3(S_N / 64, B_N * H_N), 256, 0, stream>>>(Qb, KVb, KVb + 1024, Qb);

    // out = O wo^T  (f32 out)
    gemm_bt<1><<<dim3((BS / 128) * (D_N / 128)), 256, 0, stream>>>(Qb, wb, out, BS, D_N, D_N);
}

// Round 2
// 734.353 us; speedup vs baseline: 1.2510x; 1.2510x over previous
//
#include <hip/hip_runtime.h>
#include <stdint.h>

#define B_N 2
#define S_N 2048
#define D_N 4096
#define H_N 32
#define KVH_N 8
#define HD_N 128
#define NQT (S_N / 64)
#define QK_SCALE 0.08838834764831845f

typedef __attribute__((ext_vector_type(8))) short bf16x8;
typedef __attribute__((ext_vector_type(4))) float f32x4;

__device__ __forceinline__ unsigned short f2bf(float f) {
    union { float f; unsigned u; } v; v.f = f;
    unsigned u = v.u;
    u += 0x7fffu + ((u >> 16) & 1u);   // RNE
    return (unsigned short)(u >> 16);
}
__device__ __forceinline__ float bf2f(unsigned short h) {
    union { unsigned u; float f; } v; v.u = ((unsigned)h) << 16;
    return v.f;
}

__device__ __forceinline__ void gl16(const unsigned short* g, unsigned short* l) {
    __builtin_amdgcn_global_load_lds(
        (const __attribute__((address_space(1))) void*)g,
        (__attribute__((address_space(3))) void*)l, 16, 0, 0);
}

// ---------------- f32 -> bf16 conversion (vectorized) ----------------
__global__ void __launch_bounds__(256) conv_f32_bf16(const float* __restrict__ in,
                                                     unsigned short* __restrict__ out) {
    int i = (blockIdx.x * 256 + threadIdx.x) * 4;
    float4 v = *(const float4*)(in + i);
    ushort4 o;
    o.x = f2bf(v.x); o.y = f2bf(v.y); o.z = f2bf(v.z); o.w = f2bf(v.w);
    *(ushort4*)(out + i) = o;
}

// ---------------- RoPE (in-place on bf16, pairs are adjacent) ----------------
template<int HEADS, int STRIDE>
__global__ void __launch_bounds__(256) rope_kernel(unsigned short* __restrict__ t,
                                                   const float* __restrict__ cosb,
                                                   const float* __restrict__ sinb,
                                                   float scale) {
    int p = blockIdx.x * 256 + threadIdx.x;
    int i = p & 63;                 // pair index within head dim
    int hr = p >> 6;                // head-row
    int m = hr / HEADS;             // b*S + s
    int hh = hr - m * HEADS;
    int s = m & (S_N - 1);
    size_t off = (size_t)m * STRIDE + hh * HD_N + 2 * i;
    unsigned v = *(const unsigned*)(t + off);
    float t0 = bf2f((unsigned short)(v & 0xffffu));
    float t1 = bf2f((unsigned short)(v >> 16));
    float c = cosb[s * 64 + i], sn = sinb[s * 64 + i];
    float o0 = (t0 * c - t1 * sn) * scale;
    float o1 = (t0 * sn + t1 * c) * scale;
    *(unsigned*)(t + off) = (unsigned)f2bf(o0) | ((unsigned)f2bf(o1) << 16);
}

// ---------------- NT GEMM: C[m][n] = sum_k A[m][k]*B[n][k]  (m97 structure) ----------------
template<int F32OUT>
__global__ void __launch_bounds__(256) gemm_bt(const unsigned short* __restrict__ A,
                                               const unsigned short* __restrict__ Bm,
                                               void* __restrict__ Cv,
                                               int M, int N, int K) {
    __shared__ unsigned short As[128 * 32];
    __shared__ unsigned short Bs[128 * 32];

    const int nb = N >> 7;
    const int bm = blockIdx.x / nb, bn = blockIdx.x - bm * nb;
    const int tid = threadIdx.x;
    const int w = tid >> 6, lane = tid & 63;
    const int li = lane & 15, lg = lane >> 4;
    const int wm = w >> 1, wn = w & 1;

    f32x4 acc[4][4];
#pragma unroll
    for (int i = 0; i < 4; ++i)
#pragma unroll
        for (int j = 0; j < 4; ++j) acc[i][j] = (f32x4){0.f, 0.f, 0.f, 0.f};

    const int srow = w * 32 + (lane >> 2);
    const int scol = (lane & 3) * 8;
    const unsigned short* Ag0 = A + (size_t)(bm * 128 + srow) * K + scol;
    const unsigned short* Ag1 = Ag0 + (size_t)16 * K;
    const unsigned short* Bg0 = Bm + (size_t)(bn * 128 + srow) * K + scol;
    const unsigned short* Bg1 = Bg0 + (size_t)16 * K;
    unsigned short* Asl0 = &As[(w * 2 + 0) * 512];
    unsigned short* Asl1 = &As[(w * 2 + 1) * 512];
    unsigned short* Bsl0 = &Bs[(w * 2 + 0) * 512];
    unsigned short* Bsl1 = &Bs[(w * 2 + 1) * 512];

    for (int k0 = 0; k0 < K; k0 += 32) {
        gl16(Ag0 + k0, Asl0);
        gl16(Ag1 + k0, Asl1);
        gl16(Bg0 + k0, Bsl0);
        gl16(Bg1 + k0, Bsl1);
        __syncthreads();

        bf16x8 af[4], bfr[4];
#pragma unroll
        for (int mi = 0; mi < 4; ++mi)
            af[mi] = *(const bf16x8*)&As[(wm * 64 + mi * 16 + li) * 32 + lg * 8];
#pragma unroll
        for (int ni = 0; ni < 4; ++ni)
            bfr[ni] = *(const bf16x8*)&Bs[(wn * 64 + ni * 16 + li) * 32 + lg * 8];
#pragma unroll
        for (int mi = 0; mi < 4; ++mi)
#pragma unroll
            for (int ni = 0; ni < 4; ++ni)
                acc[mi][ni] = __builtin_amdgcn_mfma_f32_16x16x32_bf16(af[mi], bfr[ni], acc[mi][ni], 0, 0, 0);
        __syncthreads();
    }

    const int r0 = bm * 128 + wm * 64 + lg * 4;
    const int c0 = bn * 128 + wn * 64 + li;
    if (F32OUT) {
        float* C = (float*)Cv;
#pragma unroll
        for (int mi = 0; mi < 4; ++mi)
#pragma unroll
            for (int ni = 0; ni < 4; ++ni)
#pragma unroll
                for (int r = 0; r < 4; ++r)
                    C[(size_t)(r0 + mi * 16 + r) * N + c0 + ni * 16] = acc[mi][ni][r];
    } else {
        unsigned short* C = (unsigned short*)Cv;
#pragma unroll
        for (int mi = 0; mi < 4; ++mi)
#pragma unroll
            for (int ni = 0; ni < 4; ++ni)
#pragma unroll
                for (int r = 0; r < 4; ++r)
                    C[(size_t)(r0 + mi * 16 + r) * N + c0 + ni * 16] = f2bf(acc[mi][ni][r]);
    }
}

// ---------------- Flash attention v2: GQA-fused, paired q-tiles, double-buffered ----------------
// Block: 512 thr (8 waves) = one (b,kvh): 4 heads x 64 q-rows. Wave w: head w>>1, q-rows (w&1)*32..+32.
// Block processes q-tiles {p, NQT-1-p} sequentially -> uniform 33 tile-iters/block; grid 16x16 = 1/CU.

__device__ __forceinline__ void stage_k_tile(const unsigned short* kt_base, // + (b*S+kt*64)*2048 + kvh*128
                                             unsigned short* ks_base, int w, int lane) {
#pragma unroll
    for (int j = 0; j < 2; ++j) {
        int row = (w * 2 + j) * 4 + (lane >> 4);
        int colb = (lane & 15) * 16;
        int key = (row & 7) << 4;
        gl16(kt_base + (size_t)row * 2048 + ((colb ^ key) >> 1),
             ks_base + (w * 2 + j) * 512);
    }
}

__device__ __forceinline__ void load_v(const unsigned short* vt_base, int tid, uint4& a0, uint4& a1) {
    int kv = (tid >> 4) * 2, d0 = (tid & 15) * 8;
    const unsigned short* vp = vt_base + (size_t)kv * 2048 + d0;
    a0 = *(const uint4*)vp;
    a1 = *(const uint4*)(vp + 2048);
}

__device__ __forceinline__ void write_v(unsigned short* vt_lds, int tid, uint4 a0, uint4 a1) {
    int kv = (tid >> 4) * 2, d0 = (tid & 15) * 8;
    union { uint4 q; unsigned short u[8]; } x0, x1;
    x0.q = a0; x1.q = a1;
#pragma unroll
    for (int jj = 0; jj < 8; ++jj) {
        int d = d0 + jj;
        unsigned pack = (unsigned)x0.u[jj] | ((unsigned)x1.u[jj] << 16);
        int key = ((d ^ (d >> 3)) & 7) << 4;
        *(unsigned*)((char*)vt_lds + d * 128 + ((kv * 2) ^ key)) = pack;
    }
}

__global__ void __launch_bounds__(512) attn_kernel(const unsigned short* __restrict__ Q,
                                                   const unsigned short* __restrict__ Kb,
                                                   const unsigned short* __restrict__ Vb,
                                                   unsigned short* __restrict__ O) {
    __shared__ unsigned short Ks[2][64 * 128];   // [kv][d], rows 256B, key=(kv&7)<<4 (src-preswizzled)
    __shared__ unsigned short Vt[2][128 * 64];   // [d][kv], rows 128B, key=((d^d>>3)&7)<<4
    __shared__ unsigned short Ps[8][32 * 64];    // per-wave [q32][kv64], rows 128B, key=(q&7)<<4

    const int pidx = blockIdx.x;          // 0..15 pair index
    const int bg = blockIdx.y;            // b*8 + kvh
    const int b = bg >> 3, kvh = bg & 7;
    const int tid = threadIdx.x;
    const int w = tid >> 6, lane = tid & 63;
    const int li = lane & 15, lg = lane >> 4;
    const int h = kvh * 4 + (w >> 1);     // global head
    const int qh = (w & 1) * 32;          // q offset within 64-row tile

    unsigned short* Pw = &Ps[w][0];
    const unsigned short* KVrow0 = Kb + (size_t)b * S_N * 2048 + kvh * 128;
    const unsigned short* Vrow0  = Vb + (size_t)b * S_N * 2048 + kvh * 128;

#pragma unroll 1
    for (int pass = 0; pass < 2; ++pass) {
        const int qt = pass ? (NQT - 1 - pidx) : pidx;
        const int nt = qt + 1;

        // Q fragments
        bf16x8 qf[2][4];
        {
            const unsigned short* qp = Q + ((size_t)b * S_N + qt * 64 + qh + li) * (H_N * HD_N)
                                         + h * HD_N + lg * 8;
#pragma unroll
            for (int mi = 0; mi < 2; ++mi)
#pragma unroll
                for (int ds = 0; ds < 4; ++ds)
                    qf[mi][ds] = *(const bf16x8*)(qp + (size_t)mi * 16 * (H_N * HD_N) + ds * 32);
        }

        float mreg[2][4], lreg[2][4];
#pragma unroll
        for (int mi = 0; mi < 2; ++mi)
#pragma unroll
            for (int r = 0; r < 4; ++r) { mreg[mi][r] = -1e30f; lreg[mi][r] = 0.f; }
        f32x4 o_acc[2][8];
#pragma unroll
        for (int mi = 0; mi < 2; ++mi)
#pragma unroll
            for (int di = 0; di < 8; ++di) o_acc[mi][di] = (f32x4){0.f, 0.f, 0.f, 0.f};

        // prologue: stage tile 0 into buf 0
        {
            stage_k_tile(KVrow0, &Ks[0][0], w, lane);
            uint4 a0, a1;
            load_v(Vrow0, tid, a0, a1);
            write_v(&Vt[0][0], tid, a0, a1);
        }
        __syncthreads();

#pragma unroll 1
        for (int t = 0; t < nt; ++t) {
            const int c = t & 1;
            const bool pre = (t + 1 < nt);
            uint4 a0, a1;
            if (pre) {
                stage_k_tile(KVrow0 + (size_t)(t + 1) * 64 * 2048, &Ks[c ^ 1][0], w, lane);
                load_v(Vrow0 + (size_t)(t + 1) * 64 * 2048, tid, a0, a1);
            }

            // ---- S = Q K^T : per wave 32 q x 64 kv ----
            f32x4 sf[2][4];
#pragma unroll
            for (int mi = 0; mi < 2; ++mi)
#pragma unroll
                for (int ni = 0; ni < 4; ++ni) sf[mi][ni] = (f32x4){0.f, 0.f, 0.f, 0.f};
#pragma unroll
            for (int ni = 0; ni < 4; ++ni) {
                const int kvc = ni * 16 + li;
                const int kkey = (kvc & 7) << 4;
                bf16x8 kf[4];
#pragma unroll
                for (int ds = 0; ds < 4; ++ds)
                    kf[ds] = *(const bf16x8*)((char*)&Ks[c][0] + kvc * 256
                                              + ((ds * 64 + lg * 16) ^ kkey));
#pragma unroll
                for (int mi = 0; mi < 2; ++mi)
#pragma unroll
                    for (int ds = 0; ds < 4; ++ds)
                        sf[mi][ni] = __builtin_amdgcn_mfma_f32_16x16x32_bf16(qf[mi][ds], kf[ds], sf[mi][ni], 0, 0, 0);
            }

            // ---- causal mask on diagonal tile ----
            if (t == qt) {
#pragma unroll
                for (int mi = 0; mi < 2; ++mi)
#pragma unroll
                    for (int ni = 0; ni < 4; ++ni) {
                        int kvc = ni * 16 + li;
#pragma unroll
                        for (int r = 0; r < 4; ++r) {
                            int qg = qh + mi * 16 + lg * 4 + r;
                            if (kvc > qg) sf[mi][ni][r] = -1e30f;
                        }
                    }
            }

            // ---- online softmax ----
            float fac[2][4];
#pragma unroll
            for (int mi = 0; mi < 2; ++mi)
#pragma unroll
                for (int r = 0; r < 4; ++r) {
                    float pm = fmaxf(fmaxf(sf[mi][0][r], sf[mi][1][r]), fmaxf(sf[mi][2][r], sf[mi][3][r]));
                    pm = fmaxf(pm, __shfl_xor(pm, 1));
                    pm = fmaxf(pm, __shfl_xor(pm, 2));
                    pm = fmaxf(pm, __shfl_xor(pm, 4));
                    pm = fmaxf(pm, __shfl_xor(pm, 8));
                    float mn = fmaxf(mreg[mi][r], pm);
                    fac[mi][r] = __expf(mreg[mi][r] - mn);
                    mreg[mi][r] = mn;
                }
#pragma unroll
            for (int mi = 0; mi < 2; ++mi)
#pragma unroll
                for (int ni = 0; ni < 4; ++ni)
#pragma unroll
                    for (int r = 0; r < 4; ++r)
                        sf[mi][ni][r] = __expf(sf[mi][ni][r] - mreg[mi][r]);
#pragma unroll
            for (int mi = 0; mi < 2; ++mi)
#pragma unroll
                for (int r = 0; r < 4; ++r) {
                    float s = sf[mi][0][r] + sf[mi][1][r] + sf[mi][2][r] + sf[mi][3][r];
                    s += __shfl_xor(s, 1);
                    s += __shfl_xor(s, 2);
                    s += __shfl_xor(s, 4);
                    s += __shfl_xor(s, 8);
                    lreg[mi][r] = lreg[mi][r] * fac[mi][r] + s;
                }
#pragma unroll
            for (int mi = 0; mi < 2; ++mi)
#pragma unroll
                for (int di = 0; di < 8; ++di)
#pragma unroll
                    for (int r = 0; r < 4; ++r) o_acc[mi][di][r] *= fac[mi][r];

            // ---- P -> LDS (wave-private; in-wave DS ordering) ----
#pragma unroll
            for (int mi = 0; mi < 2; ++mi)
#pragma unroll
                for (int ni = 0; ni < 4; ++ni) {
#pragma unroll
                    for (int r = 0; r < 4; ++r) {
                        int q = mi * 16 + lg * 4 + r;
                        int kv = ni * 16 + li;
                        *(unsigned short*)((char*)Pw + q * 128 + ((kv * 2) ^ ((q & 7) << 4)))
                            = f2bf(sf[mi][ni][r]);
                    }
                }

            // ---- O += P V ----
            {
                bf16x8 pf[2][2];
#pragma unroll
                for (int mi = 0; mi < 2; ++mi) {
                    int q = mi * 16 + li;
                    int pkey = (q & 7) << 4;
#pragma unroll
                    for (int ks = 0; ks < 2; ++ks)
                        pf[mi][ks] = *(const bf16x8*)((char*)Pw + q * 128
                                                      + ((ks * 64 + lg * 16) ^ pkey));
                }
#pragma unroll
                for (int di = 0; di < 8; ++di) {
                    int d = di * 16 + li;
                    int vkey = ((d ^ (d >> 3)) & 7) << 4;
                    bf16x8 vf[2];
#pragma unroll
                    for (int ks = 0; ks < 2; ++ks)
                        vf[ks] = *(const bf16x8*)((char*)&Vt[c][0] + d * 128
                                                  + ((ks * 64 + lg * 16) ^ vkey));
#pragma unroll
                    for (int mi = 0; mi < 2; ++mi)
#pragma unroll
                        for (int ks = 0; ks < 2; ++ks)
                            o_acc[mi][di] = __builtin_amdgcn_mfma_f32_16x16x32_bf16(pf[mi][ks], vf[ks], o_acc[mi][di], 0, 0, 0);
                }
            }

            if (pre) write_v(&Vt[c ^ 1][0], tid, a0, a1);
            __syncthreads();
        }

        // ---- epilogue ----
        float inv[2][4];
#pragma unroll
        for (int mi = 0; mi < 2; ++mi)
#pragma unroll
            for (int r = 0; r < 4; ++r) inv[mi][r] = 1.f / lreg[mi][r];
        unsigned short* op = O + ((size_t)b * S_N + qt * 64 + qh + lg * 4) * (H_N * HD_N)
                               + h * HD_N + li;
#pragma unroll
        for (int mi = 0; mi < 2; ++mi)
#pragma unroll
            for (int di = 0; di < 8; ++di)
#pragma unroll
                for (int r = 0; r < 4; ++r)
                    op[((size_t)(mi * 16 + r)) * (H_N * HD_N) + di * 16]
                        = f2bf(o_acc[mi][di][r] * inv[mi][r]);
    }
}

// ---------------- launch ----------------
extern "C" void kernel_launch(void* const* d_in, const int* in_sizes, int n_in,
                              void* d_out, int out_size, void* d_ws, size_t ws_size,
                              hipStream_t stream) {
    (void)in_sizes; (void)n_in; (void)out_size; (void)ws_size;
    const float* x  = (const float*)d_in[0];
    const float* wq = (const float*)d_in[1];
    const float* wk = (const float*)d_in[2];
    const float* wv = (const float*)d_in[3];
    const float* wo = (const float*)d_in[4];
    const float* fc = (const float*)d_in[5];
    const float* fs = (const float*)d_in[6];
    float* out = (float*)d_out;

    char* ws = (char*)d_ws;
    unsigned short* xb  = (unsigned short*)(ws);                // 33.5MB  x bf16
    unsigned short* wb  = (unsigned short*)(ws + 33554432);     // 33.5MB  wq, later wo
    unsigned short* wkv = (unsigned short*)(ws + 67108864);     // 16.8MB  [wk;wv]
    unsigned short* Qb  = (unsigned short*)(ws + 83886080);     // 33.5MB  Q, later attn-O
    unsigned short* KVb = (unsigned short*)(ws + 117440512);    // 16.8MB  [K|V] rows of 2048

    const int BS = B_N * S_N;  // 4096

    // f32 -> bf16
    conv_f32_bf16<<<dim3(BS * D_N / 1024), 256, 0, stream>>>(x, xb);
    conv_f32_bf16<<<dim3(H_N * HD_N * D_N / 1024), 256, 0, stream>>>(wq, wb);
    conv_f32_bf16<<<dim3(KVH_N * HD_N * D_N / 1024), 256, 0, stream>>>(wk, wkv);
    conv_f32_bf16<<<dim3(KVH_N * HD_N * D_N / 1024), 256, 0, stream>>>(wv, wkv + KVH_N * HD_N * D_N);

    // Q = x wq^T  (bf16 out)
    gemm_bt<0><<<dim3((BS / 128) * (D_N / 128)), 256, 0, stream>>>(xb, wb, Qb, BS, D_N, D_N);
    // wo -> wb (stream-ordered after Q gemm)
    conv_f32_bf16<<<dim3(D_N * H_N * HD_N / 1024), 256, 0, stream>>>(wo, wb);
    // [K|V] = x [wk;wv]^T  (bf16 out, N=2048)
    gemm_bt<0><<<dim3((BS / 128) * (2048 / 128)), 256, 0, stream>>>(xb, wkv, KVb, BS, 2048, D_N);

    // RoPE: Q (scale folded), K
    rope_kernel<H_N, H_N * HD_N><<<dim3(BS * H_N * 64 / 256), 256, 0, stream>>>(Qb, fc, fs, QK_SCALE);
    rope_kernel<KVH_N, 2 * KVH_N * HD_N><<<dim3(BS * KVH_N * 64 / 256), 256, 0, stream>>>(KVb, fc, fs, 1.0f);

    // attention: GQA-fused, paired q-tiles; writes O in-place over Qb (exclusive rows per block)
    attn_kernel<<<dim3(NQT / 2, B_N * KVH_N), 512, 0, stream>>>(Qb, KVb, KVb + 1024, Qb);

    // out = O wo^T  (f32 out)
    gemm_bt<1><<<dim3((BS / 128) * (D_N / 128)), 256, 0, stream>>>(Qb, wb, out, BS, D_N, D_N);
}

// Round 3
// 637.244 us; speedup vs baseline: 1.4416x; 1.1524x over previous
//
#include <hip/hip_runtime.h>
#include <stdint.h>

#define B_N 2
#define S_N 2048
#define D_N 4096
#define H_N 32
#define KVH_N 8
#define HD_N 128
#define NQT (S_N / 64)
#define QK_SCALE 0.08838834764831845f

typedef __attribute__((ext_vector_type(8))) short bf16x8;
typedef __attribute__((ext_vector_type(4))) float f32x4;

__device__ __forceinline__ unsigned short f2bf(float f) {
    union { float f; unsigned u; } v; v.f = f;
    unsigned u = v.u;
    u += 0x7fffu + ((u >> 16) & 1u);   // RNE
    return (unsigned short)(u >> 16);
}
__device__ __forceinline__ float bf2f(unsigned short h) {
    union { unsigned u; float f; } v; v.u = ((unsigned)h) << 16;
    return v.f;
}

__device__ __forceinline__ void gl16(const unsigned short* g, unsigned short* l) {
    __builtin_amdgcn_global_load_lds(
        (const __attribute__((address_space(1))) void*)g,
        (__attribute__((address_space(3))) void*)l, 16, 0, 0);
}

// ---------------- f32 -> bf16 conversion (vectorized) ----------------
__global__ void __launch_bounds__(256) conv_f32_bf16(const float* __restrict__ in,
                                                     unsigned short* __restrict__ out) {
    int i = (blockIdx.x * 256 + threadIdx.x) * 4;
    float4 v = *(const float4*)(in + i);
    ushort4 o;
    o.x = f2bf(v.x); o.y = f2bf(v.y); o.z = f2bf(v.z); o.w = f2bf(v.w);
    *(ushort4*)(out + i) = o;
}

// ---------------- RoPE (in-place on bf16, pairs are adjacent) ----------------
template<int HEADS, int STRIDE>
__global__ void __launch_bounds__(256) rope_kernel(unsigned short* __restrict__ t,
                                                   const float* __restrict__ cosb,
                                                   const float* __restrict__ sinb,
                                                   float scale) {
    int p = blockIdx.x * 256 + threadIdx.x;
    int i = p & 63;
    int hr = p >> 6;
    int m = hr / HEADS;
    int hh = hr - m * HEADS;
    int s = m & (S_N - 1);
    size_t off = (size_t)m * STRIDE + hh * HD_N + 2 * i;
    unsigned v = *(const unsigned*)(t + off);
    float t0 = bf2f((unsigned short)(v & 0xffffu));
    float t1 = bf2f((unsigned short)(v >> 16));
    float c = cosb[s * 64 + i], sn = sinb[s * 64 + i];
    float o0 = (t0 * c - t1 * sn) * scale;
    float o1 = (t0 * sn + t1 * c) * scale;
    *(unsigned*)(t + off) = (unsigned)f2bf(o0) | ((unsigned)f2bf(o1) << 16);
}

// ========================= 256x256 8-phase NT GEMM =========================
// C[m][n] = sum_k A[m][k] * B[n][k].  BM=BN=256, BK=64, 512 thr = 8 waves (2Mx4N).
// LDS: A,B tiles [256][64] bf16, st_16x32 subtiled (16r x 32c = 1024B subtiles,
// subtile order (r>>4)*2+(c>>5)), swizzle byte^=((byte>>9)&1)<<5 (row bit3 -> col bit5).
// Staging: global_load_lds linear dest + inverse-swizzled per-lane source (m173).
// Schedule (iter i computes T=2i from buf0 in ph1-4, T+1 from buf1 in ph5-8):
//   ph1: stage (T+1):A.h0->buf1  (buf1.A freed at prev ph8)
//   ph2: stage (T+1):A.h1 ; (T+2):B.h0->buf0 (buf0.B freed after ph1)
//   ph3: stage (T+2):B.h1
//   ph4: vmcnt(4) -> T+1 fully landed; barrier
//   ph5: stage (T+2):A.h0->buf0 (buf0.A freed after ph4)
//   ph6: stage (T+2):A.h1
//   ph7: stage (T+3):B.h0->buf1 (buf1.B freed after ph5)
//   ph8: stage (T+3):B.h1 ; vmcnt(4) -> T+2 fully landed
// vmcnt(4) = newest 2 half-tiles (2 wave-instrs each) may stay in flight. Never 0.

#define BAR() __builtin_amdgcn_s_barrier()
#define VMC4() asm volatile("s_waitcnt vmcnt(4)" ::: "memory")

template<int F32OUT>
__global__ void __launch_bounds__(512, 2)
gemm256(const unsigned short* __restrict__ A, const unsigned short* __restrict__ Bm,
        void* __restrict__ Cv, int M, int N, int K) {
    __shared__ unsigned short ldsA[2][16384];   // 2 x 32KB
    __shared__ unsigned short ldsB[2][16384];

    const int tid = threadIdx.x;
    const int lane = tid & 63;
    const int w = tid >> 6;
    const int li = lane & 15, lg = lane >> 4;
    const int wr = w >> 2, wc = w & 3;

    // bijective XCD swizzle (all our grids have nwg % 8 == 0)
    const int nwg = gridDim.x;
    const int cpx = nwg >> 3;
    const int wg = (blockIdx.x & 7) * cpx + (blockIdx.x >> 3);
    const int nbn = N >> 8;
    const int bm = wg / nbn, bn = wg - bm * nbn;
    const int m0 = bm << 8, n0 = bn << 8;

    // per-thread staging source coords (inverse of read swizzle; 16B chunks)
    const int rbase = ((tid >> 7) << 4) + ((tid >> 2) & 15);
    const int cstg = ((tid >> 6) & 1) * 32 + (((tid & 3) * 8) ^ (((tid >> 5) & 1) << 4));
    const unsigned short* Asrc[4];
    const unsigned short* Bsrc[4];
#pragma unroll
    for (int hj = 0; hj < 4; ++hj) {
        Asrc[hj] = A + (size_t)(m0 + hj * 64 + rbase) * K + cstg;
        Bsrc[hj] = Bm + (size_t)(n0 + hj * 64 + rbase) * K + cstg;
    }
    const int dstoff = tid * 8;      // elems; region = hj*4096 + dstoff
    const int kmask = K - 1;

    f32x4 acc[8][4];
#pragma unroll
    for (int i = 0; i < 8; ++i)
#pragma unroll
        for (int j = 0; j < 4; ++j) acc[i][j] = (f32x4){0.f, 0.f, 0.f, 0.f};

    // lane-constant column part of swizzled frag-read address (bytes)
    const int colpart = (lg * 16) ^ ((li >> 3) << 5);

#define STG(SRC, LDSBUF, H, T) do {                                         \
        int kk_ = ((T) * 64) & kmask;                                       \
        gl16(SRC[(H)*2 + 0] + kk_, &LDSBUF[((H)*2 + 0) * 4096 + dstoff]);   \
        gl16(SRC[(H)*2 + 1] + kk_, &LDSBUF[((H)*2 + 1) * 4096 + dstoff]);   \
    } while (0)

#define LDB(buf) do {                                                        \
        _Pragma("unroll")                                                    \
        for (int ni_ = 0; ni_ < 4; ++ni_) {                                  \
            _Pragma("unroll")                                                \
            for (int ks_ = 0; ks_ < 2; ++ks_)                                \
                bfr[ni_][ks_] = *(const bf16x8*)((const char*)&ldsB[buf][0]  \
                    + (wc * 4 + ni_) * 2048 + ks_ * 1024 + li * 64 + colpart); \
        }                                                                    \
    } while (0)

#define LDA(buf, q) do {                                                     \
        _Pragma("unroll")                                                    \
        for (int m_ = 0; m_ < 2; ++m_) {                                     \
            _Pragma("unroll")                                                \
            for (int ks_ = 0; ks_ < 2; ++ks_)                                \
                af[m_][ks_] = *(const bf16x8*)((const char*)&ldsA[buf][0]    \
                    + (wr * 8 + (q) * 2 + m_) * 2048 + ks_ * 1024 + li * 64 + colpart); \
        }                                                                    \
    } while (0)

#define MFMAQ(q) do {                                                        \
        __builtin_amdgcn_s_setprio(1);                                       \
        _Pragma("unroll")                                                    \
        for (int ks_ = 0; ks_ < 2; ++ks_) {                                  \
            _Pragma("unroll")                                                \
            for (int m_ = 0; m_ < 2; ++m_) {                                 \
                _Pragma("unroll")                                            \
                for (int ni_ = 0; ni_ < 4; ++ni_)                            \
                    acc[(q)*2 + m_][ni_] = __builtin_amdgcn_mfma_f32_16x16x32_bf16( \
                        af[m_][ks_], bfr[ni_][ks_], acc[(q)*2 + m_][ni_], 0, 0, 0); \
            }                                                                \
        }                                                                    \
        __builtin_amdgcn_s_setprio(0);                                       \
    } while (0)

    // ---- prologue: T0 full + T1:B ----
    STG(Asrc, ldsA[0], 0, 0); STG(Asrc, ldsA[0], 1, 0);
    STG(Bsrc, ldsB[0], 0, 0); STG(Bsrc, ldsB[0], 1, 0);
    STG(Bsrc, ldsB[1], 0, 1); STG(Bsrc, ldsB[1], 1, 1);
    VMC4();                 // T0 landed; T1:B may be in flight
    BAR();

    const int NIT = K >> 7;
    bf16x8 bfr[4][2], af[2][2];
#pragma unroll 1
    for (int i = 0; i < NIT; ++i) {
        const int T = 2 * i;
        // ph1
        LDB(0); LDA(0, 0);
        STG(Asrc, ldsA[1], 0, T + 1);
        BAR(); MFMAQ(0); BAR();
        // ph2
        LDA(0, 1);
        STG(Asrc, ldsA[1], 1, T + 1);
        STG(Bsrc, ldsB[0], 0, T + 2);
        BAR(); MFMAQ(1); BAR();
        // ph3
        LDA(0, 2);
        STG(Bsrc, ldsB[0], 1, T + 2);
        BAR(); MFMAQ(2); BAR();
        // ph4
        LDA(0, 3);
        BAR(); MFMAQ(3); VMC4(); BAR();
        // ph5
        LDB(1); LDA(1, 0);
        STG(Asrc, ldsA[0], 0, T + 2);
        BAR(); MFMAQ(0); BAR();
        // ph6
        LDA(1, 1);
        STG(Asrc, ldsA[0], 1, T + 2);
        BAR(); MFMAQ(1); BAR();
        // ph7
        LDA(1, 2);
        STG(Bsrc, ldsB[1], 0, T + 3);
        BAR(); MFMAQ(2); BAR();
        // ph8
        LDA(1, 3);
        STG(Bsrc, ldsB[1], 1, T + 3);
        BAR(); MFMAQ(3); VMC4(); BAR();
    }

    // ---- epilogue ----
    const int r0 = m0 + wr * 128 + lg * 4;
    const int c0 = n0 + wc * 64 + li;
    if (F32OUT) {
        float* C = (float*)Cv;
#pragma unroll
        for (int mi = 0; mi < 8; ++mi)
#pragma unroll
            for (int ni = 0; ni < 4; ++ni)
#pragma unroll
                for (int rr = 0; rr < 4; ++rr)
                    C[(size_t)(r0 + mi * 16 + rr) * N + c0 + ni * 16] = acc[mi][ni][rr];
    } else {
        unsigned short* C = (unsigned short*)Cv;
#pragma unroll
        for (int mi = 0; mi < 8; ++mi)
#pragma unroll
            for (int ni = 0; ni < 4; ++ni)
#pragma unroll
                for (int rr = 0; rr < 4; ++rr)
                    C[(size_t)(r0 + mi * 16 + rr) * N + c0 + ni * 16] = f2bf(acc[mi][ni][rr]);
    }
#undef STG
#undef LDB
#undef LDA
#undef MFMAQ
}

// ---------------- Flash attention: GQA-fused, paired q-tiles, double-buffered ----------------
__device__ __forceinline__ void stage_k_tile(const unsigned short* kt_base,
                                             unsigned short* ks_base, int w, int lane) {
#pragma unroll
    for (int j = 0; j < 2; ++j) {
        int row = (w * 2 + j) * 4 + (lane >> 4);
        int colb = (lane & 15) * 16;
        int key = (row & 7) << 4;
        gl16(kt_base + (size_t)row * 2048 + ((colb ^ key) >> 1),
             ks_base + (w * 2 + j) * 512);
    }
}

__device__ __forceinline__ void load_v(const unsigned short* vt_base, int tid, uint4& a0, uint4& a1) {
    int kv = (tid >> 4) * 2, d0 = (tid & 15) * 8;
    const unsigned short* vp = vt_base + (size_t)kv * 2048 + d0;
    a0 = *(const uint4*)vp;
    a1 = *(const uint4*)(vp + 2048);
}

__device__ __forceinline__ void write_v(unsigned short* vt_lds, int tid, uint4 a0, uint4 a1) {
    int kv = (tid >> 4) * 2, d0 = (tid & 15) * 8;
    union { uint4 q; unsigned short u[8]; } x0, x1;
    x0.q = a0; x1.q = a1;
#pragma unroll
    for (int jj = 0; jj < 8; ++jj) {
        int d = d0 + jj;
        unsigned pack = (unsigned)x0.u[jj] | ((unsigned)x1.u[jj] << 16);
        int key = ((d ^ (d >> 3)) & 7) << 4;
        *(unsigned*)((char*)vt_lds + d * 128 + ((kv * 2) ^ key)) = pack;
    }
}

__global__ void __launch_bounds__(512) attn_kernel(const unsigned short* __restrict__ Q,
                                                   const unsigned short* __restrict__ Kb,
                                                   const unsigned short* __restrict__ Vb,
                                                   unsigned short* __restrict__ O) {
    __shared__ unsigned short Ks[2][64 * 128];
    __shared__ unsigned short Vt[2][128 * 64];
    __shared__ unsigned short Ps[8][32 * 64];

    const int pidx = blockIdx.x;
    const int bg = blockIdx.y;
    const int b = bg >> 3, kvh = bg & 7;
    const int tid = threadIdx.x;
    const int w = tid >> 6, lane = tid & 63;
    const int li = lane & 15, lg = lane >> 4;
    const int h = kvh * 4 + (w >> 1);
    const int qh = (w & 1) * 32;

    unsigned short* Pw = &Ps[w][0];
    const unsigned short* KVrow0 = Kb + (size_t)b * S_N * 2048 + kvh * 128;
    const unsigned short* Vrow0  = Vb + (size_t)b * S_N * 2048 + kvh * 128;

#pragma unroll 1
    for (int pass = 0; pass < 2; ++pass) {
        const int qt = pass ? (NQT - 1 - pidx) : pidx;
        const int nt = qt + 1;

        bf16x8 qf[2][4];
        {
            const unsigned short* qp = Q + ((size_t)b * S_N + qt * 64 + qh + li) * (H_N * HD_N)
                                         + h * HD_N + lg * 8;
#pragma unroll
            for (int mi = 0; mi < 2; ++mi)
#pragma unroll
                for (int ds = 0; ds < 4; ++ds)
                    qf[mi][ds] = *(const bf16x8*)(qp + (size_t)mi * 16 * (H_N * HD_N) + ds * 32);
        }

        float mreg[2][4], lreg[2][4];
#pragma unroll
        for (int mi = 0; mi < 2; ++mi)
#pragma unroll
            for (int r = 0; r < 4; ++r) { mreg[mi][r] = -1e30f; lreg[mi][r] = 0.f; }
        f32x4 o_acc[2][8];
#pragma unroll
        for (int mi = 0; mi < 2; ++mi)
#pragma unroll
            for (int di = 0; di < 8; ++di) o_acc[mi][di] = (f32x4){0.f, 0.f, 0.f, 0.f};

        {
            stage_k_tile(KVrow0, &Ks[0][0], w, lane);
            uint4 a0, a1;
            load_v(Vrow0, tid, a0, a1);
            write_v(&Vt[0][0], tid, a0, a1);
        }
        __syncthreads();

#pragma unroll 1
        for (int t = 0; t < nt; ++t) {
            const int c = t & 1;
            const bool pre = (t + 1 < nt);
            uint4 a0, a1;
            if (pre) {
                stage_k_tile(KVrow0 + (size_t)(t + 1) * 64 * 2048, &Ks[c ^ 1][0], w, lane);
                load_v(Vrow0 + (size_t)(t + 1) * 64 * 2048, tid, a0, a1);
            }

            f32x4 sf[2][4];
#pragma unroll
            for (int mi = 0; mi < 2; ++mi)
#pragma unroll
                for (int ni = 0; ni < 4; ++ni) sf[mi][ni] = (f32x4){0.f, 0.f, 0.f, 0.f};
#pragma unroll
            for (int ni = 0; ni < 4; ++ni) {
                const int kvc = ni * 16 + li;
                const int kkey = (kvc & 7) << 4;
                bf16x8 kf[4];
#pragma unroll
                for (int ds = 0; ds < 4; ++ds)
                    kf[ds] = *(const bf16x8*)((char*)&Ks[c][0] + kvc * 256
                                              + ((ds * 64 + lg * 16) ^ kkey));
#pragma unroll
                for (int mi = 0; mi < 2; ++mi)
#pragma unroll
                    for (int ds = 0; ds < 4; ++ds)
                        sf[mi][ni] = __builtin_amdgcn_mfma_f32_16x16x32_bf16(qf[mi][ds], kf[ds], sf[mi][ni], 0, 0, 0);
            }

            if (t == qt) {
#pragma unroll
                for (int mi = 0; mi < 2; ++mi)
#pragma unroll
                    for (int ni = 0; ni < 4; ++ni) {
                        int kvc = ni * 16 + li;
#pragma unroll
                        for (int r = 0; r < 4; ++r) {
                            int qg = qh + mi * 16 + lg * 4 + r;
                            if (kvc > qg) sf[mi][ni][r] = -1e30f;
                        }
                    }
            }

            float fac[2][4];
#pragma unroll
            for (int mi = 0; mi < 2; ++mi)
#pragma unroll
                for (int r = 0; r < 4; ++r) {
                    float pm = fmaxf(fmaxf(sf[mi][0][r], sf[mi][1][r]), fmaxf(sf[mi][2][r], sf[mi][3][r]));
                    pm = fmaxf(pm, __shfl_xor(pm, 1));
                    pm = fmaxf(pm, __shfl_xor(pm, 2));
                    pm = fmaxf(pm, __shfl_xor(pm, 4));
                    pm = fmaxf(pm, __shfl_xor(pm, 8));
                    float mn = fmaxf(mreg[mi][r], pm);
                    fac[mi][r] = __expf(mreg[mi][r] - mn);
                    mreg[mi][r] = mn;
                }
#pragma unroll
            for (int mi = 0; mi < 2; ++mi)
#pragma unroll
                for (int ni = 0; ni < 4; ++ni)
#pragma unroll
                    for (int r = 0; r < 4; ++r)
                        sf[mi][ni][r] = __expf(sf[mi][ni][r] - mreg[mi][r]);
#pragma unroll
            for (int mi = 0; mi < 2; ++mi)
#pragma unroll
                for (int r = 0; r < 4; ++r) {
                    float s = sf[mi][0][r] + sf[mi][1][r] + sf[mi][2][r] + sf[mi][3][r];
                    s += __shfl_xor(s, 1);
                    s += __shfl_xor(s, 2);
                    s += __shfl_xor(s, 4);
                    s += __shfl_xor(s, 8);
                    lreg[mi][r] = lreg[mi][r] * fac[mi][r] + s;
                }
#pragma unroll
            for (int mi = 0; mi < 2; ++mi)
#pragma unroll
                for (int di = 0; di < 8; ++di)
#pragma unroll
                    for (int r = 0; r < 4; ++r) o_acc[mi][di][r] *= fac[mi][r];

#pragma unroll
            for (int mi = 0; mi < 2; ++mi)
#pragma unroll
                for (int ni = 0; ni < 4; ++ni) {
#pragma unroll
                    for (int r = 0; r < 4; ++r) {
                        int q = mi * 16 + lg * 4 + r;
                        int kv = ni * 16 + li;
                        *(unsigned short*)((char*)Pw + q * 128 + ((kv * 2) ^ ((q & 7) << 4)))
                            = f2bf(sf[mi][ni][r]);
                    }
                }

            {
                bf16x8 pf[2][2];
#pragma unroll
                for (int mi = 0; mi < 2; ++mi) {
                    int q = mi * 16 + li;
                    int pkey = (q & 7) << 4;
#pragma unroll
                    for (int ks = 0; ks < 2; ++ks)
                        pf[mi][ks] = *(const bf16x8*)((char*)Pw + q * 128
                                                      + ((ks * 64 + lg * 16) ^ pkey));
                }
#pragma unroll
                for (int di = 0; di < 8; ++di) {
                    int d = di * 16 + li;
                    int vkey = ((d ^ (d >> 3)) & 7) << 4;
                    bf16x8 vf[2];
#pragma unroll
                    for (int ks = 0; ks < 2; ++ks)
                        vf[ks] = *(const bf16x8*)((char*)&Vt[c][0] + d * 128
                                                  + ((ks * 64 + lg * 16) ^ vkey));
#pragma unroll
                    for (int mi = 0; mi < 2; ++mi)
#pragma unroll
                        for (int ks = 0; ks < 2; ++ks)
                            o_acc[mi][di] = __builtin_amdgcn_mfma_f32_16x16x32_bf16(pf[mi][ks], vf[ks], o_acc[mi][di], 0, 0, 0);
                }
            }

            if (pre) write_v(&Vt[c ^ 1][0], tid, a0, a1);
            __syncthreads();
        }

        float inv[2][4];
#pragma unroll
        for (int mi = 0; mi < 2; ++mi)
#pragma unroll
            for (int r = 0; r < 4; ++r) inv[mi][r] = 1.f / lreg[mi][r];
        unsigned short* op = O + ((size_t)b * S_N + qt * 64 + qh + lg * 4) * (H_N * HD_N)
                               + h * HD_N + li;
#pragma unroll
        for (int mi = 0; mi < 2; ++mi)
#pragma unroll
            for (int di = 0; di < 8; ++di)
#pragma unroll
                for (int r = 0; r < 4; ++r)
                    op[((size_t)(mi * 16 + r)) * (H_N * HD_N) + di * 16]
                        = f2bf(o_acc[mi][di][r] * inv[mi][r]);
    }
}

// ---------------- launch ----------------
extern "C" void kernel_launch(void* const* d_in, const int* in_sizes, int n_in,
                              void* d_out, int out_size, void* d_ws, size_t ws_size,
                              hipStream_t stream) {
    (void)in_sizes; (void)n_in; (void)out_size; (void)ws_size;
    const float* x  = (const float*)d_in[0];
    const float* wq = (const float*)d_in[1];
    const float* wk = (const float*)d_in[2];
    const float* wv = (const float*)d_in[3];
    const float* wo = (const float*)d_in[4];
    const float* fc = (const float*)d_in[5];
    const float* fs = (const float*)d_in[6];
    float* out = (float*)d_out;

    char* ws = (char*)d_ws;
    unsigned short* xb  = (unsigned short*)(ws);                // 33.5MB  x bf16
    unsigned short* wb  = (unsigned short*)(ws + 33554432);     // 33.5MB  wq, later wo
    unsigned short* wkv = (unsigned short*)(ws + 67108864);     // 16.8MB  [wk;wv]
    unsigned short* Qb  = (unsigned short*)(ws + 83886080);     // 33.5MB  Q, later attn-O
    unsigned short* KVb = (unsigned short*)(ws + 117440512);    // 16.8MB  [K|V] rows of 2048

    const int BS = B_N * S_N;  // 4096

    conv_f32_bf16<<<dim3(BS * D_N / 1024), 256, 0, stream>>>(x, xb);
    conv_f32_bf16<<<dim3(H_N * HD_N * D_N / 1024), 256, 0, stream>>>(wq, wb);
    conv_f32_bf16<<<dim3(KVH_N * HD_N * D_N / 1024), 256, 0, stream>>>(wk, wkv);
    conv_f32_bf16<<<dim3(KVH_N * HD_N * D_N / 1024), 256, 0, stream>>>(wv, wkv + KVH_N * HD_N * D_N);

    // Q = x wq^T  (bf16 out), 256^2 8-phase
    gemm256<0><<<dim3((BS / 256) * (D_N / 256)), 512, 0, stream>>>(xb, wb, Qb, BS, D_N, D_N);
    conv_f32_bf16<<<dim3(D_N * H_N * HD_N / 1024), 256, 0, stream>>>(wo, wb);
    // [K|V] = x [wk;wv]^T
    gemm256<0><<<dim3((BS / 256) * (2048 / 256)), 512, 0, stream>>>(xb, wkv, KVb, BS, 2048, D_N);

    rope_kernel<H_N, H_N * HD_N><<<dim3(BS * H_N * 64 / 256), 256, 0, stream>>>(Qb, fc, fs, QK_SCALE);
    rope_kernel<KVH_N, 2 * KVH_N * HD_N><<<dim3(BS * KVH_N * 64 / 256), 256, 0, stream>>>(KVb, fc, fs, 1.0f);

    attn_kernel<<<dim3(NQT / 2, B_N * KVH_N), 512, 0, stream>>>(Qb, KVb, KVb + 1024, Qb);

    // out = O wo^T (f32 out)
    gemm256<1><<<dim3((BS / 256) * (D_N / 256)), 512, 0, stream>>>(Qb, wb, out, BS, D_N, D_N);
}